// Round 12
// baseline (730.354 us; speedup 1.0000x reference)
//
#include <hip/hip_runtime.h>

#define NB 262144
#define ZD 510
#define NK 128
#define GAP_THR 0.5f

typedef _Float16 half8 __attribute__((ext_vector_type(8)));
typedef __attribute__((ext_vector_type(16))) float f32x16;

// ws layout: [0,512) csq | [512,+131072) cb16 linear image | cnt | list
#define WS_CB16_OFF 512
#define WS_CNT_OFF  131584
#define WS_LIST_OFF 131648

__device__ inline ushort f2h(float v) {
    return (ushort)__builtin_bit_cast(short, (_Float16)v);
}

// --- K0: csq (fp64, verified) + LINEAR fp16 cb image [c][code][64] + cnt=0 ---
__global__ void prep_kernel(const float* __restrict__ cb, float* __restrict__ csq,
                            ushort* __restrict__ cb16, int* __restrict__ cnt) {
    const int code = blockIdx.x;
    const int tid  = threadIdx.x;
    if (code == 0 && tid == 0) cnt[0] = 0;
    const float* row = cb + (size_t)code * ZD;

    __shared__ double ws_red[4];
    double s = 0.0;
    for (int j = 0; j < 2; ++j) {
        int d = tid + (j << 8);
        if (d < ZD) { double v = (double)row[d]; s = fma(v, v, s); }
    }
#pragma unroll
    for (int m = 1; m <= 32; m <<= 1) s += __shfl_xor(s, m, 64);
    if ((tid & 63) == 0) ws_red[tid >> 6] = s;
    __syncthreads();
    if (tid == 0) csq[code] = (float)(ws_red[0] + ws_red[1] + ws_red[2] + ws_red[3]);

    // cb16[c*8192 + code*64 + dl] = fp16(cb[code][c*64+dl]), zero-pad d>=510
    for (int s2 = tid; s2 < 512; s2 += 256) {
        int c = s2 >> 6, dl = s2 & 63;
        float v = (s2 < ZD) ? row[s2] : 0.f;
        cb16[(c << 13) + (code << 6) + dl] = f2h(v);
    }
}

// --- K1: barrier-free fp16 MFMA + argmin + flag-to-list + gather ---
// 256 thr = 4 waves x 32 rows = 128 rows/block. B read direct from L2-resident image.
// k-mapping (A and B identical, cancels): d = c*64 + hi*32 + m*8 + e.
__global__ __launch_bounds__(256, 4) void vq_fused(
    const float* __restrict__ z, const float* __restrict__ cb,
    const ushort* __restrict__ cb16, const float* __restrict__ csq,
    int* __restrict__ cnt, int* __restrict__ list, float* __restrict__ out) {
    __shared__ int km[128];

    const int tid   = threadIdx.x;
    const int lane  = tid & 63;
    const int wv    = tid >> 6;               // 0..3
    const int cmod  = lane & 31;
    const int hi    = lane >> 5;
    const int brow0 = blockIdx.x << 7;        // 128 rows/block
    const int wrow0 = brow0 + (wv << 5);      // wave's 32 rows

    f32x16 acc[4];
#pragma unroll
    for (int cf = 0; cf < 4; ++cf)
#pragma unroll
        for (int e = 0; e < 16; ++e) acc[cf][e] = 0.f;

    // lane's z stream: contiguous 32-float segment per chunk at c*64 + hi*32
    const float2* zs2 = (const float2*)(z + (size_t)(wrow0 + cmod) * ZD);

#pragma unroll
    for (int c = 0; c < 8; ++c) {
        const int f2base = (c << 5) + (hi << 4);   // float2 index of segment start
        float2 zr[16];
#pragma unroll
        for (int i = 0; i < 16; ++i) {
            // only (c==7,hi==1,i==15) touches d=510,511 -> pad
            if (c == 7 && hi == 1 && i == 15) zr[i] = make_float2(0.f, 0.f);
            else                               zr[i] = zs2[f2base + i];
        }

        const ushort* cbc = cb16 + (c << 13) + (cmod << 6) + (hi << 5);
#pragma unroll
        for (int m = 0; m < 4; ++m) {
            half8 a;
            a[0] = (_Float16)zr[4 * m + 0].x; a[1] = (_Float16)zr[4 * m + 0].y;
            a[2] = (_Float16)zr[4 * m + 1].x; a[3] = (_Float16)zr[4 * m + 1].y;
            a[4] = (_Float16)zr[4 * m + 2].x; a[5] = (_Float16)zr[4 * m + 2].y;
            a[6] = (_Float16)zr[4 * m + 3].x; a[7] = (_Float16)zr[4 * m + 3].y;
#pragma unroll
            for (int cf = 0; cf < 4; ++cf) {
                half8 b = *(const half8*)(cbc + (cf << 11) + (m << 3));  // 16B-aligned
                acc[cf] = __builtin_amdgcn_mfma_f32_32x32x16_f16(a, b, acc[cf], 0, 0, 0);
            }
        }
    }

    // ---- epilogue (verified logic; flag -> compact list) ----
    float cq[4];
#pragma unroll
    for (int cf = 0; cf < 4; ++cf) cq[cf] = csq[cf * 32 + cmod];

#pragma unroll
    for (int reg = 0; reg < 16; ++reg) {
        float bv = fmaf(-2.f, acc[0][reg], cq[0]);
        int   bk = cmod;
        float m2 = 1e30f;
#pragma unroll
        for (int cf = 1; cf < 4; ++cf) {
            float v = fmaf(-2.f, acc[cf][reg], cq[cf]);
            int  kk = cf * 32 + cmod;
            if (v < bv)      { m2 = bv; bv = v; bk = kk; }
            else if (v < m2) { m2 = v; }
        }
#pragma unroll
        for (int m = 1; m <= 16; m <<= 1) {
            float ov  = __shfl_xor(bv, m, 64);
            int   ok  = __shfl_xor(bk, m, 64);
            float om2 = __shfl_xor(m2, m, 64);
            float nm2 = fminf(fmaxf(bv, ov), fminf(m2, om2));
            bool take = (ov < bv) || (ov == bv && ok < bk);
            bv = take ? ov : bv;
            bk = take ? ok : bk;
            m2 = nm2;
        }
        if (cmod == 0) {
            int rloc = (reg & 3) + ((reg >> 2) << 3) + (hi << 2);
            km[(wv << 5) + rloc] = bk;
            if (m2 - bv < GAP_THR) {
                int idx = atomicAdd(cnt, 1);
                list[idx] = wrow0 + rloc;
            }
        }
    }
    __syncthreads();

    // gather write: 2 rows/pass, 128 threads/row, float2 (proven)
    const int half = tid >> 7, h = tid & 127;
    for (int rp = 0; rp < 64; ++rp) {
        int row = (rp << 1) + half;
        int k   = km[row] & 127;
        const float2* src = (const float2*)(cb + (size_t)k * ZD);
        float2*       dst = (float2*)(out + (size_t)(brow0 + row) * ZD);
        dst[h] = src[h];
        if (h < 127) dst[128 + h] = src[128 + h];
    }
}

// --- K2: grid-strided wave-per-flagged-row exact fp32 repair (verified r11) ---
__global__ __launch_bounds__(256) void repair(
    const float* __restrict__ z, const float* __restrict__ cb,
    const float* __restrict__ csq, const int* __restrict__ cnt,
    const int* __restrict__ list, float* __restrict__ out) {
    __shared__ float zsh[4][512];
    const int tid  = threadIdx.x;
    const int wv   = tid >> 6;
    const int lane = tid & 63;
    const int n    = cnt[0];
    const int gw0  = (blockIdx.x << 2) + wv;   // global wave id, 2048 waves

    for (int idx = gw0; idx < n; idx += 2048) {
        const int row = list[idx];
        const float* zr = z + (size_t)row * ZD;
#pragma unroll
        for (int j = 0; j < 8; ++j) {
            int d = (j << 6) + lane;
            zsh[wv][d] = (d < ZD) ? zr[d] : 0.f;
        }
        asm volatile("s_waitcnt lgkmcnt(0)" ::: "memory");

        float bv = 1e30f; int bk = 0;
        for (int c = 0; c < NK; ++c) {
            const float* cr = cb + (size_t)c * ZD;
            float s = 0.f;
#pragma unroll
            for (int j = 0; j < 8; ++j) {
                int d = (j << 6) + lane;
                float cv = (d < ZD) ? cr[d] : 0.f;
                s = fmaf(zsh[wv][d], cv, s);
            }
#pragma unroll
            for (int m = 1; m <= 32; m <<= 1) s += __shfl_xor(s, m, 64);
            float sc = fmaf(-2.f, s, csq[c]);
            if (sc < bv) { bv = sc; bk = c; }  // strict < keeps first index
        }
        const float2* src = (const float2*)(cb + (size_t)bk * ZD);
        float2*       dst = (float2*)(out + (size_t)row * ZD);
#pragma unroll
        for (int i = 0; i < 4; ++i) {
            int f2 = (i << 6) + lane;
            if (f2 < 255) dst[f2] = src[f2];
        }
    }
}

extern "C" void kernel_launch(void* const* d_in, const int* in_sizes, int n_in,
                              void* d_out, int out_size, void* d_ws, size_t ws_size,
                              hipStream_t stream) {
    const float* z  = (const float*)d_in[0];
    const float* cb = (const float*)d_in[1];
    float*  out  = (float*)d_out;
    float*  csq  = (float*)d_ws;
    ushort* cb16 = (ushort*)((char*)d_ws + WS_CB16_OFF);
    int*    cnt  = (int*)((char*)d_ws + WS_CNT_OFF);
    int*    list = (int*)((char*)d_ws + WS_LIST_OFF);

    prep_kernel<<<NK, 256, 0, stream>>>(cb, csq, cb16, cnt);
    vq_fused<<<NB / 128, 256, 0, stream>>>(z, cb, cb16, csq, cnt, list, out);
    repair<<<512, 256, 0, stream>>>(z, cb, csq, cnt, list, out);
}

// Round 14
// 575.357 us; speedup vs baseline: 1.2694x; 1.2694x over previous
//
#include <hip/hip_runtime.h>

#define NB 262144
#define ZD 510
#define NK 128
#define GAP_THR 0.5f
#define CHW 68                     // padded code-row stride in ushorts (136 B)
#define CHUNK_USH (NK * CHW)       // 8704 ushorts per 64-d chunk image
#define FULL_USH  (8 * CHUNK_USH)  // 69632 ushorts = 139264 B full image
#define FULL_U4   (FULL_USH / 8)   // 8704 uint4

typedef _Float16 half8 __attribute__((ext_vector_type(8)));
typedef __attribute__((ext_vector_type(16))) float f32x16;

// ws layout: [0,512) csq | [512,+139264) cb16 CHW image | cnt | list
#define WS_CB16_OFF 512
#define WS_CNT_OFF  139776
#define WS_LIST_OFF 139840

__device__ inline ushort f2h(float v) {
    return (ushort)__builtin_bit_cast(short, (_Float16)v);
}

// --- K0: csq (fp64, verified) + padded CHW fp16 cb image (verified r9-r11) + cnt=0 ---
__global__ void prep_kernel(const float* __restrict__ cb, float* __restrict__ csq,
                            ushort* __restrict__ cb16, int* __restrict__ cnt) {
    const int code = blockIdx.x;
    const int tid  = threadIdx.x;
    if (code == 0 && tid == 0) cnt[0] = 0;
    const float* row = cb + (size_t)code * ZD;

    __shared__ double ws_red[4];
    double s = 0.0;
    for (int j = 0; j < 2; ++j) {
        int d = tid + (j << 8);
        if (d < ZD) { double v = (double)row[d]; s = fma(v, v, s); }
    }
#pragma unroll
    for (int m = 1; m <= 32; m <<= 1) s += __shfl_xor(s, m, 64);
    if ((tid & 63) == 0) ws_red[tid >> 6] = s;
    __syncthreads();
    if (tid == 0) csq[code] = (float)(ws_red[0] + ws_red[1] + ws_red[2] + ws_red[3]);

    for (int s2 = tid; s2 < 8 * CHW; s2 += 256) {
        int ch = s2 / CHW, off = s2 - ch * CHW;
        int d  = (ch << 6) + off;
        float v = (off < 64 && d < ZD) ? row[d] : 0.f;
        cb16[ch * CHUNK_USH + code * CHW + off] = f2h(v);
    }
}

// --- K1: whole-codebook-in-LDS, barrier-free main loop ---
// 1024 thr = 16 waves x 32 rows = 512 rows/block; 1 block/CU (139 KB LDS).
// k-mapping (A and B IDENTICAL, cancels): d = c*64 + hi*32 + t*8 + e.
__global__ __launch_bounds__(1024, 4) void vq_fused(
    const float* __restrict__ z, const float* __restrict__ cb,
    const uint4* __restrict__ cb16, const float* __restrict__ csq,
    int* __restrict__ cnt, int* __restrict__ list, float* __restrict__ out) {
    __shared__ __align__(16) ushort cbb[FULL_USH];   // 139264 B
    __shared__ int km[512];

    const int tid   = threadIdx.x;
    const int lane  = tid & 63;
    const int wv    = tid >> 6;               // 0..15
    const int cmod  = lane & 31;
    const int hi    = lane >> 5;
    const int brow0 = blockIdx.x << 9;        // 512 rows/block
    const int wrow0 = brow0 + (wv << 5);      // wave's 32 rows

    // prologue: stage the full codebook image once (coalesced linear copy)
    for (int i = tid; i < FULL_U4; i += 1024)
        ((uint4*)cbb)[i] = cb16[i];
    __syncthreads();                           // the ONLY pre-gather barrier

    f32x16 acc[4];
#pragma unroll
    for (int cf = 0; cf < 4; ++cf)
#pragma unroll
        for (int e = 0; e < 16; ++e) acc[cf][e] = 0.f;

    const float2* zs2 = (const float2*)(z + (size_t)(wrow0 + cmod) * ZD);

#pragma unroll
    for (int c = 0; c < 8; ++c) {
        const int f2base = (c << 5) + (hi << 4);
        float2 zr[16];
#pragma unroll
        for (int i = 0; i < 16; ++i) {
            if (c == 7 && hi == 1 && i == 15) zr[i] = make_float2(0.f, 0.f); // d=510,511
            else                               zr[i] = zs2[f2base + i];
        }

#pragma unroll
        for (int t = 0; t < 4; ++t) {
            half8 a;   // A: d = c*64 + hi*32 + t*8 + e
            a[0] = (_Float16)zr[4 * t + 0].x; a[1] = (_Float16)zr[4 * t + 0].y;
            a[2] = (_Float16)zr[4 * t + 1].x; a[3] = (_Float16)zr[4 * t + 1].y;
            a[4] = (_Float16)zr[4 * t + 2].x; a[5] = (_Float16)zr[4 * t + 2].y;
            a[6] = (_Float16)zr[4 * t + 3].x; a[7] = (_Float16)zr[4 * t + 3].y;
#pragma unroll
            for (int cf = 0; cf < 4; ++cf) {
                // B: same mapping — within-row offset hi*32 + t*8 (FIX vs r13)
                const int bbase = c * CHUNK_USH + (cf * 32 + cmod) * CHW + (hi << 5) + (t << 3);
                union { uint2 u2[2]; half8 h; } b;
                b.u2[0] = *(const uint2*)&cbb[bbase];
                b.u2[1] = *(const uint2*)&cbb[bbase + 4];
                acc[cf] = __builtin_amdgcn_mfma_f32_32x32x16_f16(a, b.h, acc[cf], 0, 0, 0);
            }
        }
    }

    // ---- epilogue (verified logic; flag -> compact list) ----
    float cq[4];
#pragma unroll
    for (int cf = 0; cf < 4; ++cf) cq[cf] = csq[cf * 32 + cmod];

#pragma unroll
    for (int reg = 0; reg < 16; ++reg) {
        float bv = fmaf(-2.f, acc[0][reg], cq[0]);
        int   bk = cmod;
        float m2 = 1e30f;
#pragma unroll
        for (int cf = 1; cf < 4; ++cf) {
            float v = fmaf(-2.f, acc[cf][reg], cq[cf]);
            int  kk = cf * 32 + cmod;
            if (v < bv)      { m2 = bv; bv = v; bk = kk; }
            else if (v < m2) { m2 = v; }
        }
#pragma unroll
        for (int m = 1; m <= 16; m <<= 1) {
            float ov  = __shfl_xor(bv, m, 64);
            int   ok  = __shfl_xor(bk, m, 64);
            float om2 = __shfl_xor(m2, m, 64);
            float nm2 = fminf(fmaxf(bv, ov), fminf(m2, om2));
            bool take = (ov < bv) || (ov == bv && ok < bk);
            bv = take ? ov : bv;
            bk = take ? ok : bk;
            m2 = nm2;
        }
        if (cmod == 0) {
            int rloc = (reg & 3) + ((reg >> 2) << 3) + (hi << 2);
            km[(wv << 5) + rloc] = bk;
            if (m2 - bv < GAP_THR) {
                int idx = atomicAdd(cnt, 1);
                list[idx] = wrow0 + rloc;
            }
        }
    }
    __syncthreads();

    // gather write: 8 rows/pass, 128 threads/row, float2 (proven pattern)
    const int half = tid >> 7, h = tid & 127;  // half 0..7
    for (int rp = 0; rp < 64; ++rp) {
        int row = (rp << 3) + half;
        int k   = km[row] & 127;
        const float2* src = (const float2*)(cb + (size_t)k * ZD);
        float2*       dst = (float2*)(out + (size_t)(brow0 + row) * ZD);
        dst[h] = src[h];
        if (h < 127) dst[128 + h] = src[128 + h];
    }
}

// --- K2: grid-strided wave-per-flagged-row exact fp32 repair (verified r11) ---
__global__ __launch_bounds__(256) void repair(
    const float* __restrict__ z, const float* __restrict__ cb,
    const float* __restrict__ csq, const int* __restrict__ cnt,
    const int* __restrict__ list, float* __restrict__ out) {
    __shared__ float zsh[4][512];
    const int tid  = threadIdx.x;
    const int wv   = tid >> 6;
    const int lane = tid & 63;
    const int n    = cnt[0];
    const int gw0  = (blockIdx.x << 2) + wv;   // global wave id, 2048 waves

    for (int idx = gw0; idx < n; idx += 2048) {
        const int row = list[idx];
        const float* zr = z + (size_t)row * ZD;
#pragma unroll
        for (int j = 0; j < 8; ++j) {
            int d = (j << 6) + lane;
            zsh[wv][d] = (d < ZD) ? zr[d] : 0.f;
        }
        asm volatile("s_waitcnt lgkmcnt(0)" ::: "memory");

        float bv = 1e30f; int bk = 0;
        for (int c = 0; c < NK; ++c) {
            const float* cr = cb + (size_t)c * ZD;
            float s = 0.f;
#pragma unroll
            for (int j = 0; j < 8; ++j) {
                int d = (j << 6) + lane;
                float cv = (d < ZD) ? cr[d] : 0.f;
                s = fmaf(zsh[wv][d], cv, s);
            }
#pragma unroll
            for (int m = 1; m <= 32; m <<= 1) s += __shfl_xor(s, m, 64);
            float sc = fmaf(-2.f, s, csq[c]);
            if (sc < bv) { bv = sc; bk = c; }  // strict < keeps first index
        }
        const float2* src = (const float2*)(cb + (size_t)bk * ZD);
        float2*       dst = (float2*)(out + (size_t)row * ZD);
#pragma unroll
        for (int i = 0; i < 4; ++i) {
            int f2 = (i << 6) + lane;
            if (f2 < 255) dst[f2] = src[f2];
        }
    }
}

extern "C" void kernel_launch(void* const* d_in, const int* in_sizes, int n_in,
                              void* d_out, int out_size, void* d_ws, size_t ws_size,
                              hipStream_t stream) {
    const float* z  = (const float*)d_in[0];
    const float* cb = (const float*)d_in[1];
    float*  out  = (float*)d_out;
    float*  csq  = (float*)d_ws;
    ushort* cb16 = (ushort*)((char*)d_ws + WS_CB16_OFF);
    int*    cnt  = (int*)((char*)d_ws + WS_CNT_OFF);
    int*    list = (int*)((char*)d_ws + WS_LIST_OFF);

    prep_kernel<<<NK, 256, 0, stream>>>(cb, csq, cb16, cnt);
    vq_fused<<<NB / 512, 1024, 0, stream>>>(z, cb, (const uint4*)cb16, csq, cnt, list, out);
    repair<<<512, 256, 0, stream>>>(z, cb, csq, cnt, list, out);
}